// Round 1
// baseline (352.833 us; speedup 1.0000x reference)
//
#include <hip/hip_runtime.h>
#include <hip/hip_bf16.h>

typedef __attribute__((ext_vector_type(8))) short short8;
typedef __attribute__((ext_vector_type(4))) float f32x4;

#define N_ATOMS 100000
#define N_EDGES 800000
#define N_TILES (N_EDGES/16)      // 50000 tiles of 16 edges
#define WAVE_PAIRS 2048           // 1024 blocks * 4 waves / 2 (m=0/1 split)

__device__ __forceinline__ short f2bf(float x) {
    __hip_bfloat16 h = __float2bfloat16(x);
    return __builtin_bit_cast(short, h);
}

__global__ __launch_bounds__(256) void zero_out(f32x4* __restrict__ out) {
    int i = blockIdx.x * 256 + threadIdx.x;
    f32x4 z = {0.f, 0.f, 0.f, 0.f};
    out[i] = z;
}

// D_b[i][e] = sum_j K_b[i][j] * neigh[e][j]  via mfma_f32_16x16x32_bf16
//   A (rows)  = K_b i-rows (constant, staged in LDS in fragment order, hoisted to regs)
//   B (cols)  = gathered neighbor features, edge = col = lane&15 (lane-local!)
// msg[e][i] = sum_b bond[e][b] * D_b[i][e]   (bond fp32, b=16 is the bias channel)
__global__ __launch_bounds__(256, 4)
void edge_kernel(const float* __restrict__ atom,   // [N_ATOMS][32]
                 const float* __restrict__ bond,   // [N_EDGES][16]
                 const int2*  __restrict__ pair,   // [N_EDGES] (src, dst)
                 const float* __restrict__ kern,   // [16][1024]
                 const float* __restrict__ bias,   // [1024]
                 float* __restrict__ out)          // [N_ATOMS][32]
{
    // A-fragment staging: [b=0..16][m=0..1][lane][t] ; 17*2*512 bf16 = 34816 B
    __shared__ __align__(16) short alds[17*2*512];

    const int tid = threadIdx.x;
    for (int x = tid; x < 17*2*512; x += 256) {
        const int t = x & 7;
        const int l = (x >> 3) & 63;
        const int m = (x >> 9) & 1;
        const int b = x >> 10;
        const int i = m*16 + (l & 15);          // A row (output feature i)
        const int j = ((l >> 4) << 3) + t;      // A k (neighbor feature j)
        const float v = (b < 16) ? kern[b*1024 + i*32 + j] : bias[i*32 + j];
        alds[x] = f2bf(v);
    }
    __syncthreads();

    const int wave = tid >> 6;
    const int lane = tid & 63;
    const int er   = lane & 15;   // this lane's edge slot (B col, D col)
    const int jg   = lane >> 4;   // k-group
    const int wid  = blockIdx.x * 4 + wave;
    const int m    = wid & 1;     // which 16-row i-tile this wave owns
    const int pid  = wid >> 1;    // 0..2047

    short8 afr[17];
#pragma unroll
    for (int b = 0; b < 17; ++b)
        afr[b] = *(const short8*)&alds[(b*2 + m)*512 + lane*8];

    const int ibase = m*16 + jg*4;  // D row = (lane>>4)*4 + reg

    for (int tile = pid; tile < N_TILES; tile += WAVE_PAIRS) {
        const int e = tile*16 + er;
        const int2 p = pair[e];                 // x = src (segment), y = dst (gather)

        const f32x4* arow = (const f32x4*)(atom + p.y * 32);
        const f32x4 n0 = arow[jg*2];
        const f32x4 n1 = arow[jg*2 + 1];
        short8 bfrag;
        bfrag[0] = f2bf(n0[0]); bfrag[1] = f2bf(n0[1]);
        bfrag[2] = f2bf(n0[2]); bfrag[3] = f2bf(n0[3]);
        bfrag[4] = f2bf(n1[0]); bfrag[5] = f2bf(n1[1]);
        bfrag[6] = f2bf(n1[2]); bfrag[7] = f2bf(n1[3]);

        const f32x4* brow = (const f32x4*)(bond + e * 16);
        const f32x4 q0 = brow[0], q1 = brow[1], q2 = brow[2], q3 = brow[3];
        float bb[17];
        bb[0]=q0[0];  bb[1]=q0[1];  bb[2]=q0[2];  bb[3]=q0[3];
        bb[4]=q1[0];  bb[5]=q1[1];  bb[6]=q1[2];  bb[7]=q1[3];
        bb[8]=q2[0];  bb[9]=q2[1];  bb[10]=q2[2]; bb[11]=q2[3];
        bb[12]=q3[0]; bb[13]=q3[1]; bb[14]=q3[2]; bb[15]=q3[3];
        bb[16]=1.0f;                             // bias channel

        f32x4 macc = {0.f,0.f,0.f,0.f};
#pragma unroll
        for (int b = 0; b < 17; ++b) {
            f32x4 z = {0.f,0.f,0.f,0.f};
            f32x4 d = __builtin_amdgcn_mfma_f32_16x16x32_bf16(afr[b], bfrag, z, 0, 0, 0);
            macc[0] = fmaf(bb[b], d[0], macc[0]);
            macc[1] = fmaf(bb[b], d[1], macc[1]);
            macc[2] = fmaf(bb[b], d[2], macc[2]);
            macc[3] = fmaf(bb[b], d[3], macc[3]);
        }

        // lane's own edge: col = er, src = p.x; 4 consecutive i per lane
        float* obase = out + p.x * 32 + ibase;
        atomicAdd(obase + 0, macc[0]);
        atomicAdd(obase + 1, macc[1]);
        atomicAdd(obase + 2, macc[2]);
        atomicAdd(obase + 3, macc[3]);
    }
}

extern "C" void kernel_launch(void* const* d_in, const int* in_sizes, int n_in,
                              void* d_out, int out_size, void* d_ws, size_t ws_size,
                              hipStream_t stream)
{
    (void)in_sizes; (void)n_in; (void)d_ws; (void)ws_size; (void)out_size;
    const float* atom = (const float*)d_in[0];
    const float* bond = (const float*)d_in[1];
    const int2*  pair = (const int2*)d_in[2];
    const float* kern = (const float*)d_in[3];
    const float* bias = (const float*)d_in[4];
    float* out = (float*)d_out;

    zero_out<<<dim3(N_ATOMS*32/4/256), dim3(256), 0, stream>>>((f32x4*)out);
    edge_kernel<<<dim3(1024), dim3(256), 0, stream>>>(atom, bond, pair, kern, bias, out);
}

// Round 2
// 314.697 us; speedup vs baseline: 1.1212x; 1.1212x over previous
//
#include <hip/hip_runtime.h>
#include <hip/hip_bf16.h>

typedef __attribute__((ext_vector_type(8))) short short8;
typedef __attribute__((ext_vector_type(4))) short s16x4;
typedef __attribute__((ext_vector_type(4))) float f32x4;

#define N_ATOMS 100000
#define N_EDGES 800000
#define N_TILES (N_EDGES/16)      // 50000 tiles of 16 edges
#define WAVE_PAIRS 2048           // 1024 blocks * 4 waves / 2 (m=0/1 split)

// ---- ws layout (bytes) ----
#define WS_MSG     0ULL                      // bf16 msg [N_EDGES][32] = 51,200,000
#define WS_OFFS    51200000ULL               // int offsets [N_ATOMS+1]
#define WS_COUNTS  51600016ULL               // int counts [N_ATOMS]
#define WS_CURSOR  52000016ULL               // int cursor [N_ATOMS]  (contiguous w/ counts)
#define WS_SLOT    52400016ULL               // int slot [N_EDGES]
#define WS_NEED    55600016ULL

__device__ __forceinline__ short f2bf(float x) {
    __hip_bfloat16 h = __float2bfloat16(x);
    return __builtin_bit_cast(short, h);
}
__device__ __forceinline__ float bf2f(short b) {
    unsigned u = ((unsigned)(unsigned short)b) << 16;
    return __builtin_bit_cast(float, u);
}

// ---------------- CSR build ----------------
__global__ __launch_bounds__(256) void zero_ints(int* __restrict__ p, int n) {
    int i = blockIdx.x * 256 + threadIdx.x;
    if (i < n) p[i] = 0;
}

__global__ __launch_bounds__(256) void hist_kernel(const int2* __restrict__ pair,
                                                   int* __restrict__ counts) {
    int e = blockIdx.x * 256 + threadIdx.x;
    if (e < N_EDGES) atomicAdd(&counts[pair[e].x], 1);
}

__global__ __launch_bounds__(1024) void scan_kernel(const int* __restrict__ counts,
                                                    int* __restrict__ offsets) {
    const int tid = threadIdx.x;
    const int CH = (N_ATOMS + 1023) / 1024;   // 98
    const int start = tid * CH;
    const int end = min(start + CH, N_ATOMS);
    int s = 0;
    for (int i = start; i < end; ++i) s += counts[i];

    __shared__ int swarp[16];
    const int lane = tid & 63, wv = tid >> 6;
    int v = s;
#pragma unroll
    for (int off = 1; off < 64; off <<= 1) {
        int u = __shfl_up(v, off);
        if (lane >= off) v += u;
    }
    if (lane == 63) swarp[wv] = v;
    __syncthreads();
    if (wv == 0) {
        int w = (lane < 16) ? swarp[lane] : 0;
#pragma unroll
        for (int off = 1; off < 16; off <<= 1) {
            int u = __shfl_up(w, off);
            if (lane >= off) w += u;
        }
        if (lane < 16) swarp[lane] = w;
    }
    __syncthreads();
    int base = ((wv > 0) ? swarp[wv - 1] : 0) + (v - s);   // exclusive prefix
    for (int i = start; i < end; ++i) { offsets[i] = base; base += counts[i]; }
    if (tid == 1023) offsets[N_ATOMS] = base;
}

__global__ __launch_bounds__(256) void scatter_kernel(const int2* __restrict__ pair,
                                                      const int* __restrict__ offsets,
                                                      int* __restrict__ cursor,
                                                      int* __restrict__ slot) {
    int e = blockIdx.x * 256 + threadIdx.x;
    if (e < N_EDGES) {
        int s = pair[e].x;
        int k = atomicAdd(&cursor[s], 1);
        slot[e] = offsets[s] + k;
    }
}

// ---------------- phase A: per-edge messages via MFMA ----------------
// D_b[i][e] = sum_j K_b[i][j]*neigh[e][j]  (mfma 16x16x32 bf16, edge = col = lane&15)
// msg[e][i] = sum_b bond[e][b]*D_b[i][e]  (fp32 VALU, b=16 is bias channel)
// store bf16 msg at CSR slot[e] -> phase B reads contiguously per atom.
__global__ __launch_bounds__(256, 4)
void edge_msg_kernel(const float* __restrict__ atom,
                     const float* __restrict__ bond,
                     const int2*  __restrict__ pair,
                     const float* __restrict__ kern,
                     const float* __restrict__ bias,
                     const int*   __restrict__ slot,
                     short*       __restrict__ msg)
{
    __shared__ __align__(16) short alds[17*2*512];
    const int tid = threadIdx.x;
    for (int x = tid; x < 17*2*512; x += 256) {
        const int t = x & 7;
        const int l = (x >> 3) & 63;
        const int m = (x >> 9) & 1;
        const int b = x >> 10;
        const int i = m*16 + (l & 15);
        const int j = ((l >> 4) << 3) + t;
        const float v = (b < 16) ? kern[b*1024 + i*32 + j] : bias[i*32 + j];
        alds[x] = f2bf(v);
    }
    __syncthreads();

    const int wave = tid >> 6;
    const int lane = tid & 63;
    const int er   = lane & 15;
    const int jg   = lane >> 4;
    const int wid  = blockIdx.x * 4 + wave;
    const int m    = wid & 1;
    const int pid  = wid >> 1;

    short8 afr[17];
#pragma unroll
    for (int b = 0; b < 17; ++b)
        afr[b] = *(const short8*)&alds[(b*2 + m)*512 + lane*8];

    const int ibase = m*16 + jg*4;

    for (int tile = pid; tile < N_TILES; tile += WAVE_PAIRS) {
        const int e = tile*16 + er;
        const int2 p = pair[e];
        const int sl = slot[e];

        const f32x4* arow = (const f32x4*)(atom + p.y * 32);
        const f32x4 n0 = arow[jg*2];
        const f32x4 n1 = arow[jg*2 + 1];
        short8 bfrag;
        bfrag[0] = f2bf(n0[0]); bfrag[1] = f2bf(n0[1]);
        bfrag[2] = f2bf(n0[2]); bfrag[3] = f2bf(n0[3]);
        bfrag[4] = f2bf(n1[0]); bfrag[5] = f2bf(n1[1]);
        bfrag[6] = f2bf(n1[2]); bfrag[7] = f2bf(n1[3]);

        const f32x4* brow = (const f32x4*)(bond + e * 16);
        const f32x4 q0 = brow[0], q1 = brow[1], q2 = brow[2], q3 = brow[3];
        float bb[17];
        bb[0]=q0[0];  bb[1]=q0[1];  bb[2]=q0[2];  bb[3]=q0[3];
        bb[4]=q1[0];  bb[5]=q1[1];  bb[6]=q1[2];  bb[7]=q1[3];
        bb[8]=q2[0];  bb[9]=q2[1];  bb[10]=q2[2]; bb[11]=q2[3];
        bb[12]=q3[0]; bb[13]=q3[1]; bb[14]=q3[2]; bb[15]=q3[3];
        bb[16]=1.0f;

        f32x4 macc = {0.f,0.f,0.f,0.f};
#pragma unroll
        for (int b = 0; b < 17; ++b) {
            f32x4 z = {0.f,0.f,0.f,0.f};
            f32x4 d = __builtin_amdgcn_mfma_f32_16x16x32_bf16(afr[b], bfrag, z, 0, 0, 0);
            macc[0] = fmaf(bb[b], d[0], macc[0]);
            macc[1] = fmaf(bb[b], d[1], macc[1]);
            macc[2] = fmaf(bb[b], d[2], macc[2]);
            macc[3] = fmaf(bb[b], d[3], macc[3]);
        }

        s16x4 mv;
        mv[0] = f2bf(macc[0]); mv[1] = f2bf(macc[1]);
        mv[2] = f2bf(macc[2]); mv[3] = f2bf(macc[3]);
        *(s16x4*)&msg[sl*32 + ibase] = mv;
    }
}

// ---------------- phase B: per-atom gather-sum (atomic-free) ----------------
__global__ __launch_bounds__(256) void gather_kernel(const short* __restrict__ msg,
                                                     const int* __restrict__ offsets,
                                                     float* __restrict__ out) {
    const int tid = threadIdx.x;
    const int a = blockIdx.x * 32 + (tid >> 3);
    const int sub = (tid & 7) * 4;
    if (a >= N_ATOMS) return;
    const int b0 = offsets[a], b1 = offsets[a + 1];
    f32x4 acc = {0.f, 0.f, 0.f, 0.f};
    for (int k = b0; k < b1; ++k) {
        s16x4 mv = *(const s16x4*)&msg[k*32 + sub];
        acc[0] += bf2f(mv[0]);
        acc[1] += bf2f(mv[1]);
        acc[2] += bf2f(mv[2]);
        acc[3] += bf2f(mv[3]);
    }
    *(f32x4*)&out[a*32 + sub] = acc;
}

// ---------------- fallback (R1 atomic version, known-passing) ----------------
__global__ __launch_bounds__(256) void zero_out(f32x4* __restrict__ out) {
    int i = blockIdx.x * 256 + threadIdx.x;
    f32x4 z = {0.f, 0.f, 0.f, 0.f};
    out[i] = z;
}

__global__ __launch_bounds__(256, 4)
void edge_kernel_atomic(const float* __restrict__ atom, const float* __restrict__ bond,
                        const int2* __restrict__ pair, const float* __restrict__ kern,
                        const float* __restrict__ bias, float* __restrict__ out)
{
    __shared__ __align__(16) short alds[17*2*512];
    const int tid = threadIdx.x;
    for (int x = tid; x < 17*2*512; x += 256) {
        const int t = x & 7;
        const int l = (x >> 3) & 63;
        const int m = (x >> 9) & 1;
        const int b = x >> 10;
        const int i = m*16 + (l & 15);
        const int j = ((l >> 4) << 3) + t;
        const float v = (b < 16) ? kern[b*1024 + i*32 + j] : bias[i*32 + j];
        alds[x] = f2bf(v);
    }
    __syncthreads();
    const int wave = tid >> 6, lane = tid & 63;
    const int er = lane & 15, jg = lane >> 4;
    const int wid = blockIdx.x * 4 + wave;
    const int m = wid & 1, pid = wid >> 1;
    short8 afr[17];
#pragma unroll
    for (int b = 0; b < 17; ++b)
        afr[b] = *(const short8*)&alds[(b*2 + m)*512 + lane*8];
    const int ibase = m*16 + jg*4;
    for (int tile = pid; tile < N_TILES; tile += WAVE_PAIRS) {
        const int e = tile*16 + er;
        const int2 p = pair[e];
        const f32x4* arow = (const f32x4*)(atom + p.y * 32);
        const f32x4 n0 = arow[jg*2];
        const f32x4 n1 = arow[jg*2 + 1];
        short8 bfrag;
        bfrag[0] = f2bf(n0[0]); bfrag[1] = f2bf(n0[1]);
        bfrag[2] = f2bf(n0[2]); bfrag[3] = f2bf(n0[3]);
        bfrag[4] = f2bf(n1[0]); bfrag[5] = f2bf(n1[1]);
        bfrag[6] = f2bf(n1[2]); bfrag[7] = f2bf(n1[3]);
        const f32x4* brow = (const f32x4*)(bond + e * 16);
        const f32x4 q0 = brow[0], q1 = brow[1], q2 = brow[2], q3 = brow[3];
        float bb[17];
        bb[0]=q0[0];  bb[1]=q0[1];  bb[2]=q0[2];  bb[3]=q0[3];
        bb[4]=q1[0];  bb[5]=q1[1];  bb[6]=q1[2];  bb[7]=q1[3];
        bb[8]=q2[0];  bb[9]=q2[1];  bb[10]=q2[2]; bb[11]=q2[3];
        bb[12]=q3[0]; bb[13]=q3[1]; bb[14]=q3[2]; bb[15]=q3[3];
        bb[16]=1.0f;
        f32x4 macc = {0.f,0.f,0.f,0.f};
#pragma unroll
        for (int b = 0; b < 17; ++b) {
            f32x4 z = {0.f,0.f,0.f,0.f};
            f32x4 d = __builtin_amdgcn_mfma_f32_16x16x32_bf16(afr[b], bfrag, z, 0, 0, 0);
            macc[0] = fmaf(bb[b], d[0], macc[0]);
            macc[1] = fmaf(bb[b], d[1], macc[1]);
            macc[2] = fmaf(bb[b], d[2], macc[2]);
            macc[3] = fmaf(bb[b], d[3], macc[3]);
        }
        float* obase = out + p.x * 32 + ibase;
        atomicAdd(obase + 0, macc[0]);
        atomicAdd(obase + 1, macc[1]);
        atomicAdd(obase + 2, macc[2]);
        atomicAdd(obase + 3, macc[3]);
    }
}

extern "C" void kernel_launch(void* const* d_in, const int* in_sizes, int n_in,
                              void* d_out, int out_size, void* d_ws, size_t ws_size,
                              hipStream_t stream)
{
    (void)in_sizes; (void)n_in; (void)out_size;
    const float* atom = (const float*)d_in[0];
    const float* bond = (const float*)d_in[1];
    const int2*  pair = (const int2*)d_in[2];
    const float* kern = (const float*)d_in[3];
    const float* bias = (const float*)d_in[4];
    float* out = (float*)d_out;

    if (ws_size < WS_NEED) {
        // fallback: known-passing atomic version
        zero_out<<<dim3(N_ATOMS*32/4/256), dim3(256), 0, stream>>>((f32x4*)out);
        edge_kernel_atomic<<<dim3(1024), dim3(256), 0, stream>>>(atom, bond, pair, kern, bias, out);
        return;
    }

    char* ws = (char*)d_ws;
    short* msg    = (short*)(ws + WS_MSG);
    int* offsets  = (int*)(ws + WS_OFFS);
    int* counts   = (int*)(ws + WS_COUNTS);
    // cursor is contiguous after counts; zero both with one kernel
    int* cursor   = (int*)(ws + WS_CURSOR);
    int* slot     = (int*)(ws + WS_SLOT);

    const int eb = (N_EDGES + 255) / 256;          // 3125
    zero_ints<<<dim3((2*N_ATOMS + 255)/256), dim3(256), 0, stream>>>(counts, 2*N_ATOMS);
    hist_kernel<<<dim3(eb), dim3(256), 0, stream>>>(pair, counts);
    scan_kernel<<<dim3(1), dim3(1024), 0, stream>>>(counts, offsets);
    scatter_kernel<<<dim3(eb), dim3(256), 0, stream>>>(pair, offsets, cursor, slot);
    edge_msg_kernel<<<dim3(1024), dim3(256), 0, stream>>>(atom, bond, pair, kern, bias, slot, msg);
    gather_kernel<<<dim3((N_ATOMS + 31)/32), dim3(256), 0, stream>>>(msg, offsets, out);
}

// Round 3
// 163.394 us; speedup vs baseline: 2.1594x; 1.9260x over previous
//
#include <hip/hip_runtime.h>
#include <hip/hip_bf16.h>

typedef __attribute__((ext_vector_type(8))) short short8;
typedef __attribute__((ext_vector_type(4))) short s16x4;
typedef __attribute__((ext_vector_type(4))) float f32x4;

#define N_ATOMS 100000
#define N_EDGES 800000
#define N_TILES (N_EDGES/16)      // 50000 tiles of 16 edges
#define WAVE_PAIRS 2048           // 1024 blocks * 4 waves / 2 (m=0/1 split)
#define N_CHUNKS ((N_ATOMS + 255) / 256)   // 391 scan chunks

// ---- ws layout (bytes) ----
#define WS_MSG     0ULL                      // bf16 msg [N_EDGES][32] = 51,200,000
#define WS_OFFS    51200000ULL               // int offsets [N_ATOMS+1]
#define WS_COUNTS  51600016ULL               // int counts [N_ATOMS]
#define WS_CURSOR  52000016ULL               // int cursor [N_ATOMS]  (contiguous w/ counts)
#define WS_SLOT    52400016ULL               // int slot [N_EDGES]
#define WS_PART    55600016ULL               // int partials [512]
#define WS_NEED    55602064ULL

__device__ __forceinline__ short f2bf(float x) {
    __hip_bfloat16 h = __float2bfloat16(x);
    return __builtin_bit_cast(short, h);
}
__device__ __forceinline__ float bf2f(short b) {
    unsigned u = ((unsigned)(unsigned short)b) << 16;
    return __builtin_bit_cast(float, u);
}

// ---------------- CSR build ----------------
__global__ __launch_bounds__(256) void zero_ints(int* __restrict__ p, int n) {
    int i = blockIdx.x * 256 + threadIdx.x;
    if (i < n) p[i] = 0;
}

__global__ __launch_bounds__(256) void hist_kernel(const int2* __restrict__ pair,
                                                   int* __restrict__ counts) {
    int e = blockIdx.x * 256 + threadIdx.x;
    if (e < N_EDGES) atomicAdd(&counts[pair[e].x], 1);
}

// 3-phase hierarchical exclusive scan of counts[N_ATOMS] -> offsets[N_ATOMS+1]
__global__ __launch_bounds__(256) void scan_part(const int* __restrict__ counts,
                                                 int* __restrict__ partials) {
    const int tid = threadIdx.x;
    const int i = blockIdx.x * 256 + tid;
    int v = (i < N_ATOMS) ? counts[i] : 0;
#pragma unroll
    for (int off = 1; off < 64; off <<= 1) v += __shfl_xor(v, off);
    __shared__ int ws4[4];
    const int lane = tid & 63, wv = tid >> 6;
    if (lane == 0) ws4[wv] = v;
    __syncthreads();
    if (tid == 0) partials[blockIdx.x] = ws4[0] + ws4[1] + ws4[2] + ws4[3];
}

__global__ __launch_bounds__(512) void scan_mid(int* __restrict__ partials) {
    const int tid = threadIdx.x;
    const int lane = tid & 63, wv = tid >> 6;
    int v = (tid < N_CHUNKS) ? partials[tid] : 0;
    int inc = v;
#pragma unroll
    for (int off = 1; off < 64; off <<= 1) {
        int u = __shfl_up(inc, off);
        if (lane >= off) inc += u;
    }
    __shared__ int ws8[8];
    if (lane == 63) ws8[wv] = inc;
    __syncthreads();
    int base = 0;
#pragma unroll
    for (int k = 0; k < 8; ++k) base += (k < wv) ? ws8[k] : 0;
    if (tid < N_CHUNKS) partials[tid] = base + inc - v;   // exclusive
}

__global__ __launch_bounds__(256) void scan_final(const int* __restrict__ counts,
                                                  const int* __restrict__ partials,
                                                  int* __restrict__ offsets) {
    const int tid = threadIdx.x;
    const int i = blockIdx.x * 256 + tid;
    const int lane = tid & 63, wv = tid >> 6;
    int c = (i < N_ATOMS) ? counts[i] : 0;
    int inc = c;
#pragma unroll
    for (int off = 1; off < 64; off <<= 1) {
        int u = __shfl_up(inc, off);
        if (lane >= off) inc += u;
    }
    __shared__ int ws4[4];
    if (lane == 63) ws4[wv] = inc;
    __syncthreads();
    int base = partials[blockIdx.x];
#pragma unroll
    for (int k = 0; k < 4; ++k) base += (k < wv) ? ws4[k] : 0;
    const int off = base + inc - c;                        // exclusive prefix
    if (i < N_ATOMS) offsets[i] = off;
    if (i == N_ATOMS - 1) offsets[N_ATOMS] = off + c;
}

__global__ __launch_bounds__(256) void scatter_kernel(const int2* __restrict__ pair,
                                                      const int* __restrict__ offsets,
                                                      int* __restrict__ cursor,
                                                      int* __restrict__ slot) {
    int e = blockIdx.x * 256 + threadIdx.x;
    if (e < N_EDGES) {
        int s = pair[e].x;
        int k = atomicAdd(&cursor[s], 1);
        slot[e] = offsets[s] + k;
    }
}

// ---------------- phase A: per-edge messages via MFMA ----------------
// D_b[i][e] = sum_j K_b[i][j]*neigh[e][j]  (mfma 16x16x32 bf16, edge = col = lane&15)
// msg[e][i] = sum_b bond[e][b]*D_b[i][e]  (fp32 VALU, b=16 is bias channel)
// store bf16 msg at CSR slot[e] -> phase B reads contiguously per atom.
__global__ __launch_bounds__(256, 4)
void edge_msg_kernel(const float* __restrict__ atom,
                     const float* __restrict__ bond,
                     const int2*  __restrict__ pair,
                     const float* __restrict__ kern,
                     const float* __restrict__ bias,
                     const int*   __restrict__ slot,
                     short*       __restrict__ msg)
{
    __shared__ __align__(16) short alds[17*2*512];
    const int tid = threadIdx.x;
    for (int x = tid; x < 17*2*512; x += 256) {
        const int t = x & 7;
        const int l = (x >> 3) & 63;
        const int m = (x >> 9) & 1;
        const int b = x >> 10;
        const int i = m*16 + (l & 15);
        const int j = ((l >> 4) << 3) + t;
        const float v = (b < 16) ? kern[b*1024 + i*32 + j] : bias[i*32 + j];
        alds[x] = f2bf(v);
    }
    __syncthreads();

    const int wave = tid >> 6;
    const int lane = tid & 63;
    const int er   = lane & 15;
    const int jg   = lane >> 4;
    const int wid  = blockIdx.x * 4 + wave;
    const int m    = wid & 1;
    const int pid  = wid >> 1;

    short8 afr[17];
#pragma unroll
    for (int b = 0; b < 17; ++b)
        afr[b] = *(const short8*)&alds[(b*2 + m)*512 + lane*8];

    const int ibase = m*16 + jg*4;

    for (int tile = pid; tile < N_TILES; tile += WAVE_PAIRS) {
        const int e = tile*16 + er;
        const int2 p = pair[e];
        const int sl = slot[e];

        const f32x4* arow = (const f32x4*)(atom + p.y * 32);
        const f32x4 n0 = arow[jg*2];
        const f32x4 n1 = arow[jg*2 + 1];
        short8 bfrag;
        bfrag[0] = f2bf(n0[0]); bfrag[1] = f2bf(n0[1]);
        bfrag[2] = f2bf(n0[2]); bfrag[3] = f2bf(n0[3]);
        bfrag[4] = f2bf(n1[0]); bfrag[5] = f2bf(n1[1]);
        bfrag[6] = f2bf(n1[2]); bfrag[7] = f2bf(n1[3]);

        const f32x4* brow = (const f32x4*)(bond + e * 16);
        const f32x4 q0 = brow[0], q1 = brow[1], q2 = brow[2], q3 = brow[3];
        float bb[17];
        bb[0]=q0[0];  bb[1]=q0[1];  bb[2]=q0[2];  bb[3]=q0[3];
        bb[4]=q1[0];  bb[5]=q1[1];  bb[6]=q1[2];  bb[7]=q1[3];
        bb[8]=q2[0];  bb[9]=q2[1];  bb[10]=q2[2]; bb[11]=q2[3];
        bb[12]=q3[0]; bb[13]=q3[1]; bb[14]=q3[2]; bb[15]=q3[3];
        bb[16]=1.0f;

        f32x4 macc = {0.f,0.f,0.f,0.f};
#pragma unroll
        for (int b = 0; b < 17; ++b) {
            f32x4 z = {0.f,0.f,0.f,0.f};
            f32x4 d = __builtin_amdgcn_mfma_f32_16x16x32_bf16(afr[b], bfrag, z, 0, 0, 0);
            macc[0] = fmaf(bb[b], d[0], macc[0]);
            macc[1] = fmaf(bb[b], d[1], macc[1]);
            macc[2] = fmaf(bb[b], d[2], macc[2]);
            macc[3] = fmaf(bb[b], d[3], macc[3]);
        }

        s16x4 mv;
        mv[0] = f2bf(macc[0]); mv[1] = f2bf(macc[1]);
        mv[2] = f2bf(macc[2]); mv[3] = f2bf(macc[3]);
        *(s16x4*)&msg[sl*32 + ibase] = mv;
    }
}

// ---------------- phase B: per-atom gather-sum (atomic-free) ----------------
__global__ __launch_bounds__(256) void gather_kernel(const short* __restrict__ msg,
                                                     const int* __restrict__ offsets,
                                                     float* __restrict__ out) {
    const int tid = threadIdx.x;
    const int a = blockIdx.x * 32 + (tid >> 3);
    const int sub = (tid & 7) * 4;
    if (a >= N_ATOMS) return;
    const int b0 = offsets[a], b1 = offsets[a + 1];
    f32x4 acc = {0.f, 0.f, 0.f, 0.f};
    for (int k = b0; k < b1; ++k) {
        s16x4 mv = *(const s16x4*)&msg[k*32 + sub];
        acc[0] += bf2f(mv[0]);
        acc[1] += bf2f(mv[1]);
        acc[2] += bf2f(mv[2]);
        acc[3] += bf2f(mv[3]);
    }
    *(f32x4*)&out[a*32 + sub] = acc;
}

// ---------------- fallback (R1 atomic version, known-passing) ----------------
__global__ __launch_bounds__(256) void zero_out(f32x4* __restrict__ out) {
    int i = blockIdx.x * 256 + threadIdx.x;
    f32x4 z = {0.f, 0.f, 0.f, 0.f};
    out[i] = z;
}

__global__ __launch_bounds__(256, 4)
void edge_kernel_atomic(const float* __restrict__ atom, const float* __restrict__ bond,
                        const int2* __restrict__ pair, const float* __restrict__ kern,
                        const float* __restrict__ bias, float* __restrict__ out)
{
    __shared__ __align__(16) short alds[17*2*512];
    const int tid = threadIdx.x;
    for (int x = tid; x < 17*2*512; x += 256) {
        const int t = x & 7;
        const int l = (x >> 3) & 63;
        const int m = (x >> 9) & 1;
        const int b = x >> 10;
        const int i = m*16 + (l & 15);
        const int j = ((l >> 4) << 3) + t;
        const float v = (b < 16) ? kern[b*1024 + i*32 + j] : bias[i*32 + j];
        alds[x] = f2bf(v);
    }
    __syncthreads();
    const int wave = tid >> 6, lane = tid & 63;
    const int er = lane & 15, jg = lane >> 4;
    const int wid = blockIdx.x * 4 + wave;
    const int m = wid & 1, pid = wid >> 1;
    short8 afr[17];
#pragma unroll
    for (int b = 0; b < 17; ++b)
        afr[b] = *(const short8*)&alds[(b*2 + m)*512 + lane*8];
    const int ibase = m*16 + jg*4;
    for (int tile = pid; tile < N_TILES; tile += WAVE_PAIRS) {
        const int e = tile*16 + er;
        const int2 p = pair[e];
        const f32x4* arow = (const f32x4*)(atom + p.y * 32);
        const f32x4 n0 = arow[jg*2];
        const f32x4 n1 = arow[jg*2 + 1];
        short8 bfrag;
        bfrag[0] = f2bf(n0[0]); bfrag[1] = f2bf(n0[1]);
        bfrag[2] = f2bf(n0[2]); bfrag[3] = f2bf(n0[3]);
        bfrag[4] = f2bf(n1[0]); bfrag[5] = f2bf(n1[1]);
        bfrag[6] = f2bf(n1[2]); bfrag[7] = f2bf(n1[3]);
        const f32x4* brow = (const f32x4*)(bond + e * 16);
        const f32x4 q0 = brow[0], q1 = brow[1], q2 = brow[2], q3 = brow[3];
        float bb[17];
        bb[0]=q0[0];  bb[1]=q0[1];  bb[2]=q0[2];  bb[3]=q0[3];
        bb[4]=q1[0];  bb[5]=q1[1];  bb[6]=q1[2];  bb[7]=q1[3];
        bb[8]=q2[0];  bb[9]=q2[1];  bb[10]=q2[2]; bb[11]=q2[3];
        bb[12]=q3[0]; bb[13]=q3[1]; bb[14]=q3[2]; bb[15]=q3[3];
        bb[16]=1.0f;
        f32x4 macc = {0.f,0.f,0.f,0.f};
#pragma unroll
        for (int b = 0; b < 17; ++b) {
            f32x4 z = {0.f,0.f,0.f,0.f};
            f32x4 d = __builtin_amdgcn_mfma_f32_16x16x32_bf16(afr[b], bfrag, z, 0, 0, 0);
            macc[0] = fmaf(bb[b], d[0], macc[0]);
            macc[1] = fmaf(bb[b], d[1], macc[1]);
            macc[2] = fmaf(bb[b], d[2], macc[2]);
            macc[3] = fmaf(bb[b], d[3], macc[3]);
        }
        float* obase = out + p.x * 32 + ibase;
        atomicAdd(obase + 0, macc[0]);
        atomicAdd(obase + 1, macc[1]);
        atomicAdd(obase + 2, macc[2]);
        atomicAdd(obase + 3, macc[3]);
    }
}

extern "C" void kernel_launch(void* const* d_in, const int* in_sizes, int n_in,
                              void* d_out, int out_size, void* d_ws, size_t ws_size,
                              hipStream_t stream)
{
    (void)in_sizes; (void)n_in; (void)out_size;
    const float* atom = (const float*)d_in[0];
    const float* bond = (const float*)d_in[1];
    const int2*  pair = (const int2*)d_in[2];
    const float* kern = (const float*)d_in[3];
    const float* bias = (const float*)d_in[4];
    float* out = (float*)d_out;

    if (ws_size < WS_NEED) {
        // fallback: known-passing atomic version
        zero_out<<<dim3(N_ATOMS*32/4/256), dim3(256), 0, stream>>>((f32x4*)out);
        edge_kernel_atomic<<<dim3(1024), dim3(256), 0, stream>>>(atom, bond, pair, kern, bias, out);
        return;
    }

    char* ws = (char*)d_ws;
    short* msg    = (short*)(ws + WS_MSG);
    int* offsets  = (int*)(ws + WS_OFFS);
    int* counts   = (int*)(ws + WS_COUNTS);
    int* cursor   = (int*)(ws + WS_CURSOR);
    int* slot     = (int*)(ws + WS_SLOT);
    int* partials = (int*)(ws + WS_PART);

    const int eb = (N_EDGES + 255) / 256;          // 3125
    zero_ints<<<dim3((2*N_ATOMS + 255)/256), dim3(256), 0, stream>>>(counts, 2*N_ATOMS);
    hist_kernel<<<dim3(eb), dim3(256), 0, stream>>>(pair, counts);
    scan_part<<<dim3(N_CHUNKS), dim3(256), 0, stream>>>(counts, partials);
    scan_mid<<<dim3(1), dim3(512), 0, stream>>>(partials);
    scan_final<<<dim3(N_CHUNKS), dim3(256), 0, stream>>>(counts, partials, offsets);
    scatter_kernel<<<dim3(eb), dim3(256), 0, stream>>>(pair, offsets, cursor, slot);
    edge_msg_kernel<<<dim3(1024), dim3(256), 0, stream>>>(atom, bond, pair, kern, bias, slot, msg);
    gather_kernel<<<dim3((N_ATOMS + 31)/32), dim3(256), 0, stream>>>(msg, offsets, out);
}

// Round 4
// 120.802 us; speedup vs baseline: 2.9208x; 1.3526x over previous
//
#include <hip/hip_runtime.h>
#include <hip/hip_bf16.h>

typedef __attribute__((ext_vector_type(8))) short short8;
typedef __attribute__((ext_vector_type(4))) short s16x4;
typedef __attribute__((ext_vector_type(4))) float f32x4;

#define N_ATOMS 100000
#define N_EDGES 800000
#define N_TILES (N_EDGES/16)      // 50000 tiles of 16 edges
#define WAVE_PAIRS 2048           // 1024 blocks * 4 waves / 2 (m=0/1 split)
#define N_CHUNKS ((N_ATOMS + 255) / 256)   // 391 scan chunks

// ---- ws layout (bytes) ----
#define WS_MSG     0ULL                      // bf16 msg [N_EDGES][32] = 51,200,000
#define WS_OFFS    51200000ULL               // int offsets [N_ATOMS+1]
#define WS_COUNTS  51600016ULL               // int counts [N_ATOMS]
#define WS_CURSOR  52000016ULL               // (unused now)
#define WS_SLOT    52400016ULL               // int slot [N_EDGES]
#define WS_PART    55600016ULL               // int partials [512]
#define WS_NEED    55602064ULL

__device__ __forceinline__ short f2bf(float x) {
    __hip_bfloat16 h = __float2bfloat16(x);
    return __builtin_bit_cast(short, h);
}
__device__ __forceinline__ float bf2f(short b) {
    unsigned u = ((unsigned)(unsigned short)b) << 16;
    return __builtin_bit_cast(float, u);
}

// ---------------- CSR build ----------------
__global__ __launch_bounds__(256) void zero_ints(int* __restrict__ p, int n) {
    int i = blockIdx.x * 256 + threadIdx.x;
    if (i < n) p[i] = 0;
}

// pass1: slot[e] = rank of edge within its atom (single atomic pass)
__global__ __launch_bounds__(256) void rank_kernel(const int2* __restrict__ pair,
                                                   int* __restrict__ counts,
                                                   int* __restrict__ slot) {
    int e = blockIdx.x * 256 + threadIdx.x;
    if (e < N_EDGES) slot[e] = atomicAdd(&counts[pair[e].x], 1);
}

// 3-phase hierarchical exclusive scan of counts[N_ATOMS] -> offsets[N_ATOMS+1]
__global__ __launch_bounds__(256) void scan_part(const int* __restrict__ counts,
                                                 int* __restrict__ partials) {
    const int tid = threadIdx.x;
    const int i = blockIdx.x * 256 + tid;
    int v = (i < N_ATOMS) ? counts[i] : 0;
#pragma unroll
    for (int off = 1; off < 64; off <<= 1) v += __shfl_xor(v, off);
    __shared__ int ws4[4];
    const int lane = tid & 63, wv = tid >> 6;
    if (lane == 0) ws4[wv] = v;
    __syncthreads();
    if (tid == 0) partials[blockIdx.x] = ws4[0] + ws4[1] + ws4[2] + ws4[3];
}

__global__ __launch_bounds__(512) void scan_mid(int* __restrict__ partials) {
    const int tid = threadIdx.x;
    const int lane = tid & 63, wv = tid >> 6;
    int v = (tid < N_CHUNKS) ? partials[tid] : 0;
    int inc = v;
#pragma unroll
    for (int off = 1; off < 64; off <<= 1) {
        int u = __shfl_up(inc, off);
        if (lane >= off) inc += u;
    }
    __shared__ int ws8[8];
    if (lane == 63) ws8[wv] = inc;
    __syncthreads();
    int base = 0;
#pragma unroll
    for (int k = 0; k < 8; ++k) base += (k < wv) ? ws8[k] : 0;
    if (tid < N_CHUNKS) partials[tid] = base + inc - v;   // exclusive
}

__global__ __launch_bounds__(256) void scan_final(const int* __restrict__ counts,
                                                  const int* __restrict__ partials,
                                                  int* __restrict__ offsets) {
    const int tid = threadIdx.x;
    const int i = blockIdx.x * 256 + tid;
    const int lane = tid & 63, wv = tid >> 6;
    int c = (i < N_ATOMS) ? counts[i] : 0;
    int inc = c;
#pragma unroll
    for (int off = 1; off < 64; off <<= 1) {
        int u = __shfl_up(inc, off);
        if (lane >= off) inc += u;
    }
    __shared__ int ws4[4];
    if (lane == 63) ws4[wv] = inc;
    __syncthreads();
    int base = partials[blockIdx.x];
#pragma unroll
    for (int k = 0; k < 4; ++k) base += (k < wv) ? ws4[k] : 0;
    const int off = base + inc - c;                        // exclusive prefix
    if (i < N_ATOMS) offsets[i] = off;
    if (i == N_ATOMS - 1) offsets[N_ATOMS] = off + c;
}

// pass2: finalize slot (atomic-free)
__global__ __launch_bounds__(256) void slot_add_kernel(const int2* __restrict__ pair,
                                                       const int* __restrict__ offsets,
                                                       int* __restrict__ slot) {
    int e = blockIdx.x * 256 + threadIdx.x;
    if (e < N_EDGES) slot[e] += offsets[pair[e].x];
}

// ---------------- phase A: per-edge messages via MFMA (pipelined) ----------------
// D_b[i][e] = sum_j K_b[i][j]*neigh[e][j]  (mfma 16x16x32 bf16, edge = col = lane&15)
// msg[e][i] = sum_b bond[e][b]*D_b[i][e]  (fp32 VALU, b=16 is bias channel)
// 2-deep software pipeline: t+1 pair/slot/bond issued at top, t+1 atom gather after MFMA.
// bond loaded as ONE lane-remapped dwordx4/lane (16 line-requests vs 64 sector-requests),
// bounced through padded wave-private LDS. Bias A-frag (b=16) read from LDS each iter
// to keep regs at 64 VGPR + 64 AGPR = 128 -> 4 waves/SIMD.
__global__ __launch_bounds__(256, 4)
void edge_msg_kernel(const float* __restrict__ atom,
                     const float* __restrict__ bond,
                     const int2*  __restrict__ pair,
                     const float* __restrict__ kern,
                     const float* __restrict__ bias,
                     const int*   __restrict__ slot,
                     short*       __restrict__ msg)
{
    __shared__ __align__(16) short alds[17*2*512];          // 34816 B
    __shared__ __align__(16) float blds[4][16*20];          // 5120 B (80B stride/edge)

    const int tid = threadIdx.x;
    for (int x = tid; x < 17*2*512; x += 256) {
        const int t = x & 7;
        const int l = (x >> 3) & 63;
        const int m = (x >> 9) & 1;
        const int b = x >> 10;
        const int i = m*16 + (l & 15);
        const int j = ((l >> 4) << 3) + t;
        const float v = (b < 16) ? kern[b*1024 + i*32 + j] : bias[i*32 + j];
        alds[x] = f2bf(v);
    }
    __syncthreads();

    const int wave = tid >> 6;
    const int lane = tid & 63;
    const int er   = lane & 15;
    const int jg   = lane >> 4;
    const int wid  = blockIdx.x * 4 + wave;
    const int m    = wid & 1;
    const int pid  = wid >> 1;

    short8 afr[16];
#pragma unroll
    for (int b = 0; b < 16; ++b)
        afr[b] = *(const short8*)&alds[(b*2 + m)*512 + lane*8];
    const short* afr16p = &alds[(16*2 + m)*512 + lane*8];   // bias frag, LDS-resident

    const int ibase = m*16 + jg*4;

    // bond staging lane map: lane l covers edge (l>>2), 16B quarter (l&3)
    float* bw = &blds[wave][(lane >> 2)*20 + (lane & 3)*4];
    const float* brd = &blds[wave][er*20];

    // ---- prologue: tile t0 ----
    int t0 = pid;
    int2  pc = pair[t0*16 + er];
    int   sc = slot[t0*16 + er];
    f32x4 bvc = *(const f32x4*)(bond + t0*256 + lane*4);
    f32x4 n0 = *(const f32x4*)(atom + pc.y*32 + jg*8);
    f32x4 n1 = *(const f32x4*)(atom + pc.y*32 + jg*8 + 4);
    *(f32x4*)bw = bvc;

    for (int t = pid; t < N_TILES; t += WAVE_PAIRS) {
        const int tn  = t + WAVE_PAIRS;
        const int tcl = (tn < N_TILES) ? tn : (N_TILES - 1);   // clamped prefetch

        // issue next-tile independent loads
        const int2  pn  = pair[tcl*16 + er];
        const int   sn  = slot[tcl*16 + er];
        const f32x4 bvn = *(const f32x4*)(bond + tcl*256 + lane*4);

        // current bond coeffs from LDS
        const f32x4 q0 = *(const f32x4*)(brd + 0);
        const f32x4 q1 = *(const f32x4*)(brd + 4);
        const f32x4 q2 = *(const f32x4*)(brd + 8);
        const f32x4 q3 = *(const f32x4*)(brd + 12);
        const short8 af16 = *(const short8*)afr16p;

        short8 bfrag;
        bfrag[0] = f2bf(n0[0]); bfrag[1] = f2bf(n0[1]);
        bfrag[2] = f2bf(n0[2]); bfrag[3] = f2bf(n0[3]);
        bfrag[4] = f2bf(n1[0]); bfrag[5] = f2bf(n1[1]);
        bfrag[6] = f2bf(n1[2]); bfrag[7] = f2bf(n1[3]);

        float bb[16];
        bb[0]=q0[0];  bb[1]=q0[1];  bb[2]=q0[2];  bb[3]=q0[3];
        bb[4]=q1[0];  bb[5]=q1[1];  bb[6]=q1[2];  bb[7]=q1[3];
        bb[8]=q2[0];  bb[9]=q2[1];  bb[10]=q2[2]; bb[11]=q2[3];
        bb[12]=q3[0]; bb[13]=q3[1]; bb[14]=q3[2]; bb[15]=q3[3];

        f32x4 macc = {0.f,0.f,0.f,0.f};
        f32x4 z = {0.f,0.f,0.f,0.f};
#pragma unroll
        for (int b = 0; b < 16; ++b) {
            f32x4 d = __builtin_amdgcn_mfma_f32_16x16x32_bf16(afr[b], bfrag, z, 0, 0, 0);
            macc[0] = fmaf(bb[b], d[0], macc[0]);
            macc[1] = fmaf(bb[b], d[1], macc[1]);
            macc[2] = fmaf(bb[b], d[2], macc[2]);
            macc[3] = fmaf(bb[b], d[3], macc[3]);
        }
        {   // bias channel (bb == 1)
            f32x4 d = __builtin_amdgcn_mfma_f32_16x16x32_bf16(af16, bfrag, z, 0, 0, 0);
            macc[0] += d[0]; macc[1] += d[1]; macc[2] += d[2]; macc[3] += d[3];
        }

        // next-tile dependent loads (pn arrived during MFMA block)
        const f32x4 n0n = *(const f32x4*)(atom + pn.y*32 + jg*8);
        const f32x4 n1n = *(const f32x4*)(atom + pn.y*32 + jg*8 + 4);

        // stage next bond into LDS (bvn arrived during MFMA block; reads of q done)
        *(f32x4*)bw = bvn;

        // store current msg
        s16x4 mv;
        mv[0] = f2bf(macc[0]); mv[1] = f2bf(macc[1]);
        mv[2] = f2bf(macc[2]); mv[3] = f2bf(macc[3]);
        *(s16x4*)&msg[sc*32 + ibase] = mv;

        // rotate
        pc = pn; sc = sn; n0 = n0n; n1 = n1n;
    }
}

// ---------------- phase B: per-atom gather-sum (atomic-free, 2x unroll) ----------------
__global__ __launch_bounds__(256) void gather_kernel(const short* __restrict__ msg,
                                                     const int* __restrict__ offsets,
                                                     float* __restrict__ out) {
    const int tid = threadIdx.x;
    const int a = blockIdx.x * 32 + (tid >> 3);
    const int sub = (tid & 7) * 4;
    if (a >= N_ATOMS) return;
    const int b0 = offsets[a], b1 = offsets[a + 1];
    f32x4 acc0 = {0.f, 0.f, 0.f, 0.f};
    f32x4 acc1 = {0.f, 0.f, 0.f, 0.f};
    int k = b0;
    for (; k + 1 < b1; k += 2) {
        s16x4 mv0 = *(const s16x4*)&msg[k*32 + sub];
        s16x4 mv1 = *(const s16x4*)&msg[(k+1)*32 + sub];
        acc0[0] += bf2f(mv0[0]); acc0[1] += bf2f(mv0[1]);
        acc0[2] += bf2f(mv0[2]); acc0[3] += bf2f(mv0[3]);
        acc1[0] += bf2f(mv1[0]); acc1[1] += bf2f(mv1[1]);
        acc1[2] += bf2f(mv1[2]); acc1[3] += bf2f(mv1[3]);
    }
    if (k < b1) {
        s16x4 mv0 = *(const s16x4*)&msg[k*32 + sub];
        acc0[0] += bf2f(mv0[0]); acc0[1] += bf2f(mv0[1]);
        acc0[2] += bf2f(mv0[2]); acc0[3] += bf2f(mv0[3]);
    }
    acc0[0] += acc1[0]; acc0[1] += acc1[1]; acc0[2] += acc1[2]; acc0[3] += acc1[3];
    *(f32x4*)&out[a*32 + sub] = acc0;
}

// ---------------- fallback (R1 atomic version, known-passing) ----------------
__global__ __launch_bounds__(256) void zero_out(f32x4* __restrict__ out) {
    int i = blockIdx.x * 256 + threadIdx.x;
    f32x4 z = {0.f, 0.f, 0.f, 0.f};
    out[i] = z;
}

__global__ __launch_bounds__(256, 4)
void edge_kernel_atomic(const float* __restrict__ atom, const float* __restrict__ bond,
                        const int2* __restrict__ pair, const float* __restrict__ kern,
                        const float* __restrict__ bias, float* __restrict__ out)
{
    __shared__ __align__(16) short alds[17*2*512];
    const int tid = threadIdx.x;
    for (int x = tid; x < 17*2*512; x += 256) {
        const int t = x & 7;
        const int l = (x >> 3) & 63;
        const int m = (x >> 9) & 1;
        const int b = x >> 10;
        const int i = m*16 + (l & 15);
        const int j = ((l >> 4) << 3) + t;
        const float v = (b < 16) ? kern[b*1024 + i*32 + j] : bias[i*32 + j];
        alds[x] = f2bf(v);
    }
    __syncthreads();
    const int wave = tid >> 6, lane = tid & 63;
    const int er = lane & 15, jg = lane >> 4;
    const int wid = blockIdx.x * 4 + wave;
    const int m = wid & 1, pid = wid >> 1;
    short8 afr[17];
#pragma unroll
    for (int b = 0; b < 17; ++b)
        afr[b] = *(const short8*)&alds[(b*2 + m)*512 + lane*8];
    const int ibase = m*16 + jg*4;
    for (int tile = pid; tile < N_TILES; tile += WAVE_PAIRS) {
        const int e = tile*16 + er;
        const int2 p = pair[e];
        const f32x4* arow = (const f32x4*)(atom + p.y * 32);
        const f32x4 n0 = arow[jg*2];
        const f32x4 n1 = arow[jg*2 + 1];
        short8 bfrag;
        bfrag[0] = f2bf(n0[0]); bfrag[1] = f2bf(n0[1]);
        bfrag[2] = f2bf(n0[2]); bfrag[3] = f2bf(n0[3]);
        bfrag[4] = f2bf(n1[0]); bfrag[5] = f2bf(n1[1]);
        bfrag[6] = f2bf(n1[2]); bfrag[7] = f2bf(n1[3]);
        const f32x4* brow = (const f32x4*)(bond + e * 16);
        const f32x4 q0 = brow[0], q1 = brow[1], q2 = brow[2], q3 = brow[3];
        float bb[17];
        bb[0]=q0[0];  bb[1]=q0[1];  bb[2]=q0[2];  bb[3]=q0[3];
        bb[4]=q1[0];  bb[5]=q1[1];  bb[6]=q1[2];  bb[7]=q1[3];
        bb[8]=q2[0];  bb[9]=q2[1];  bb[10]=q2[2]; bb[11]=q2[3];
        bb[12]=q3[0]; bb[13]=q3[1]; bb[14]=q3[2]; bb[15]=q3[3];
        bb[16]=1.0f;
        f32x4 macc = {0.f,0.f,0.f,0.f};
#pragma unroll
        for (int b = 0; b < 17; ++b) {
            f32x4 z = {0.f,0.f,0.f,0.f};
            f32x4 d = __builtin_amdgcn_mfma_f32_16x16x32_bf16(afr[b], bfrag, z, 0, 0, 0);
            macc[0] = fmaf(bb[b], d[0], macc[0]);
            macc[1] = fmaf(bb[b], d[1], macc[1]);
            macc[2] = fmaf(bb[b], d[2], macc[2]);
            macc[3] = fmaf(bb[b], d[3], macc[3]);
        }
        float* obase = out + p.x * 32 + ibase;
        atomicAdd(obase + 0, macc[0]);
        atomicAdd(obase + 1, macc[1]);
        atomicAdd(obase + 2, macc[2]);
        atomicAdd(obase + 3, macc[3]);
    }
}

extern "C" void kernel_launch(void* const* d_in, const int* in_sizes, int n_in,
                              void* d_out, int out_size, void* d_ws, size_t ws_size,
                              hipStream_t stream)
{
    (void)in_sizes; (void)n_in; (void)out_size;
    const float* atom = (const float*)d_in[0];
    const float* bond = (const float*)d_in[1];
    const int2*  pair = (const int2*)d_in[2];
    const float* kern = (const float*)d_in[3];
    const float* bias = (const float*)d_in[4];
    float* out = (float*)d_out;

    if (ws_size < WS_NEED) {
        zero_out<<<dim3(N_ATOMS*32/4/256), dim3(256), 0, stream>>>((f32x4*)out);
        edge_kernel_atomic<<<dim3(1024), dim3(256), 0, stream>>>(atom, bond, pair, kern, bias, out);
        return;
    }

    char* ws = (char*)d_ws;
    short* msg    = (short*)(ws + WS_MSG);
    int* offsets  = (int*)(ws + WS_OFFS);
    int* counts   = (int*)(ws + WS_COUNTS);
    int* slot     = (int*)(ws + WS_SLOT);
    int* partials = (int*)(ws + WS_PART);

    const int eb = (N_EDGES + 255) / 256;          // 3125
    zero_ints<<<dim3((N_ATOMS + 255)/256), dim3(256), 0, stream>>>(counts, N_ATOMS);
    rank_kernel<<<dim3(eb), dim3(256), 0, stream>>>(pair, counts, slot);
    scan_part<<<dim3(N_CHUNKS), dim3(256), 0, stream>>>(counts, partials);
    scan_mid<<<dim3(1), dim3(512), 0, stream>>>(partials);
    scan_final<<<dim3(N_CHUNKS), dim3(256), 0, stream>>>(counts, partials, offsets);
    slot_add_kernel<<<dim3(eb), dim3(256), 0, stream>>>(pair, offsets, slot);
    edge_msg_kernel<<<dim3(1024), dim3(256), 0, stream>>>(atom, bond, pair, kern, bias, slot, msg);
    gather_kernel<<<dim3((N_ATOMS + 31)/32), dim3(256), 0, stream>>>(msg, offsets, out);
}

// Round 5
// 117.163 us; speedup vs baseline: 3.0115x; 1.0311x over previous
//
#include <hip/hip_runtime.h>
#include <hip/hip_bf16.h>

typedef __attribute__((ext_vector_type(8))) short short8;
typedef __attribute__((ext_vector_type(4))) short s16x4;
typedef __attribute__((ext_vector_type(4))) float f32x4;

#define N_ATOMS 100000
#define N_EDGES 800000
#define N_TILES (N_EDGES/16)      // 50000 tiles of 16 edges
#define WAVE_PAIRS 2048           // 1024 blocks * 4 waves / 2 (m=0/1 split)
#define N_CHUNKS ((N_ATOMS + 255) / 256)   // 391 scan chunks

// ---- ws layout (bytes) ----
#define WS_MSG     0ULL                      // bf16 msg [N_EDGES][32] = 51,200,000
#define WS_OFFS    51200000ULL               // int offsets [N_ATOMS+1]
#define WS_COUNTS  51600016ULL               // int counts [N_ATOMS]
#define WS_EDATA   52000016ULL               // int2 edata [N_EDGES] {dst, slot}
#define WS_RANK    58400016ULL               // int rank [N_EDGES]
#define WS_PART    61600016ULL               // int partials [512]
#define WS_NEED    61602064ULL

__device__ __forceinline__ short f2bf(float x) {
    __hip_bfloat16 h = __float2bfloat16(x);
    return __builtin_bit_cast(short, h);
}
__device__ __forceinline__ float bf2f(short b) {
    unsigned u = ((unsigned)(unsigned short)b) << 16;
    return __builtin_bit_cast(float, u);
}

// ---------------- CSR build ----------------
__global__ __launch_bounds__(256) void zero_ints(int* __restrict__ p, int n) {
    int i = blockIdx.x * 256 + threadIdx.x;
    if (i < n) p[i] = 0;
}

// pass1: rank[e] = arrival rank of edge within its src atom
__global__ __launch_bounds__(256) void rank_kernel(const int2* __restrict__ pair,
                                                   int* __restrict__ counts,
                                                   int* __restrict__ rank) {
    int e = blockIdx.x * 256 + threadIdx.x;
    if (e < N_EDGES) rank[e] = atomicAdd(&counts[pair[e].x], 1);
}

// 3-phase hierarchical exclusive scan of counts[N_ATOMS] -> offsets[N_ATOMS+1]
__global__ __launch_bounds__(256) void scan_part(const int* __restrict__ counts,
                                                 int* __restrict__ partials) {
    const int tid = threadIdx.x;
    const int i = blockIdx.x * 256 + tid;
    int v = (i < N_ATOMS) ? counts[i] : 0;
#pragma unroll
    for (int off = 1; off < 64; off <<= 1) v += __shfl_xor(v, off);
    __shared__ int ws4[4];
    const int lane = tid & 63, wv = tid >> 6;
    if (lane == 0) ws4[wv] = v;
    __syncthreads();
    if (tid == 0) partials[blockIdx.x] = ws4[0] + ws4[1] + ws4[2] + ws4[3];
}

__global__ __launch_bounds__(512) void scan_mid(int* __restrict__ partials) {
    const int tid = threadIdx.x;
    const int lane = tid & 63, wv = tid >> 6;
    int v = (tid < N_CHUNKS) ? partials[tid] : 0;
    int inc = v;
#pragma unroll
    for (int off = 1; off < 64; off <<= 1) {
        int u = __shfl_up(inc, off);
        if (lane >= off) inc += u;
    }
    __shared__ int ws8[8];
    if (lane == 63) ws8[wv] = inc;
    __syncthreads();
    int base = 0;
#pragma unroll
    for (int k = 0; k < 8; ++k) base += (k < wv) ? ws8[k] : 0;
    if (tid < N_CHUNKS) partials[tid] = base + inc - v;   // exclusive
}

__global__ __launch_bounds__(256) void scan_final(const int* __restrict__ counts,
                                                  const int* __restrict__ partials,
                                                  int* __restrict__ offsets) {
    const int tid = threadIdx.x;
    const int i = blockIdx.x * 256 + tid;
    const int lane = tid & 63, wv = tid >> 6;
    int c = (i < N_ATOMS) ? counts[i] : 0;
    int inc = c;
#pragma unroll
    for (int off = 1; off < 64; off <<= 1) {
        int u = __shfl_up(inc, off);
        if (lane >= off) inc += u;
    }
    __shared__ int ws4[4];
    if (lane == 63) ws4[wv] = inc;
    __syncthreads();
    int base = partials[blockIdx.x];
#pragma unroll
    for (int k = 0; k < 4; ++k) base += (k < wv) ? ws4[k] : 0;
    const int off = base + inc - c;                        // exclusive prefix
    if (i < N_ATOMS) offsets[i] = off;
    if (i == N_ATOMS - 1) offsets[N_ATOMS] = off + c;
}

// pass2: edata[e] = {dst, CSR slot}  (one fused load stream for edge_msg)
__global__ __launch_bounds__(256) void edata_kernel(const int2* __restrict__ pair,
                                                    const int* __restrict__ offsets,
                                                    const int* __restrict__ rank,
                                                    int2* __restrict__ edata) {
    int e = blockIdx.x * 256 + threadIdx.x;
    if (e < N_EDGES) {
        int2 p = pair[e];
        int2 d;
        d.x = p.y;                          // dst (gather row)
        d.y = offsets[p.x] + rank[e];       // CSR slot
        edata[e] = d;
    }
}

// ---------------- phase A: per-edge messages via MFMA (3-stage pipeline) ----------------
// D_b[i][e] = sum_j K_b[i][j]*neigh[e][j]  (mfma 16x16x32 bf16, edge = col = lane&15)
// msg[e][i] = sum_b bond[e][b]*D_b[i][e]  (fp32 VALU, bias via extra unit-coeff MFMA)
// Schedule per iteration t (each load covered by >= 1 full iteration):
//   top:    issue edata/bond for t+2; issue atom gather for t+1 (edata arrived 1 iter ago)
//   middle: ds_read bond[t] coeffs; cvt bfrag (gathered 1 iter ago); 17 MFMA + fmaf
//   bottom: ds_write bond[t+1] (regs arrived 1 iter ago, double-buffered); store msg[t]
__global__ __launch_bounds__(256, 3)
void edge_msg_kernel(const float* __restrict__ atom,
                     const float* __restrict__ bond,
                     const float* __restrict__ kern,
                     const float* __restrict__ bias,
                     const int2*  __restrict__ edata,
                     short*       __restrict__ msg)
{
    // kern staging (32768 B) aliased with bond double-buffer (2*4*320 floats = 10240 B)
    __shared__ __align__(16) char smem[32768];
    short* klds = (short*)smem;            // [16][2][512] bf16 kern frags
    float* blds = (float*)smem;            // [2][4][320]  bond dbuf (80B stride/edge)

    const int tid = threadIdx.x;
    for (int x = tid; x < 16*2*512; x += 256) {
        const int t = x & 7;
        const int l = (x >> 3) & 63;
        const int m = (x >> 9) & 1;
        const int b = x >> 10;
        const int i = m*16 + (l & 15);
        const int j = ((l >> 4) << 3) + t;
        klds[x] = f2bf(kern[b*1024 + i*32 + j]);
    }
    __syncthreads();

    const int wave = tid >> 6;
    const int lane = tid & 63;
    const int er   = lane & 15;
    const int jg   = lane >> 4;
    const int wid  = blockIdx.x * 4 + wave;
    const int m    = wid & 1;
    const int pid  = wid >> 1;

    short8 afr[16];
#pragma unroll
    for (int b = 0; b < 16; ++b)
        afr[b] = *(const short8*)&klds[(b*2 + m)*512 + lane*8];

    // bias frag direct from global (one-time)
    short8 af16;
    {
        const float* bp = bias + (m*16 + er)*32 + jg*8;
        const f32x4 z0 = *(const f32x4*)bp;
        const f32x4 z1 = *(const f32x4*)(bp + 4);
        af16[0]=f2bf(z0[0]); af16[1]=f2bf(z0[1]); af16[2]=f2bf(z0[2]); af16[3]=f2bf(z0[3]);
        af16[4]=f2bf(z1[0]); af16[5]=f2bf(z1[1]); af16[6]=f2bf(z1[2]); af16[7]=f2bf(z1[3]);
    }
    __syncthreads();   // all waves done reading klds; safe to reuse as bond dbuf

    const int ibase = m*16 + jg*4;

    // bond staging lane map: lane l covers edge (l>>2), 16B quarter (l&3)
    float* bwA = blds + (0*4 + wave)*320 + (lane >> 2)*20 + (lane & 3)*4;
    float* bwB = blds + (1*4 + wave)*320 + (lane >> 2)*20 + (lane & 3)*4;
    const float* brA = blds + (0*4 + wave)*320 + er*20;
    const float* brB = blds + (1*4 + wave)*320 + er*20;

    const int last = N_TILES - 1;

    // ---- prologue ----
    const int tA = pid;
    const int tB = (pid + WAVE_PAIRS <= last) ? pid + WAVE_PAIRS : last;
    int2  e0 = edata[tA*16 + er];
    f32x4 bv0 = *(const f32x4*)(bond + tA*256 + lane*4);
    int2  e1 = edata[tB*16 + er];
    f32x4 bv1 = *(const f32x4*)(bond + tB*256 + lane*4);
    f32x4 n0 = *(const f32x4*)(atom + e0.x*32 + jg*8);
    f32x4 n1 = *(const f32x4*)(atom + e0.x*32 + jg*8 + 4);
    *(f32x4*)bwA = bv0;

    for (int t = pid; t < N_TILES; t += WAVE_PAIRS) {
        // issue t+2 loads
        int tn2 = t + 2*WAVE_PAIRS; tn2 = (tn2 <= last) ? tn2 : last;
        const int2  e2  = edata[tn2*16 + er];
        const f32x4 bv2 = *(const f32x4*)(bond + tn2*256 + lane*4);

        // issue gather for t+1 (e1 arrived one iteration ago)
        const f32x4 n0n = *(const f32x4*)(atom + e1.x*32 + jg*8);
        const f32x4 n1n = *(const f32x4*)(atom + e1.x*32 + jg*8 + 4);

        // bond coeffs for t from LDS (written >= 1 iteration ago)
        const f32x4 q0 = *(const f32x4*)(brA + 0);
        const f32x4 q1 = *(const f32x4*)(brA + 4);
        const f32x4 q2 = *(const f32x4*)(brA + 8);
        const f32x4 q3 = *(const f32x4*)(brA + 12);

        short8 bfrag;
        bfrag[0] = f2bf(n0[0]); bfrag[1] = f2bf(n0[1]);
        bfrag[2] = f2bf(n0[2]); bfrag[3] = f2bf(n0[3]);
        bfrag[4] = f2bf(n1[0]); bfrag[5] = f2bf(n1[1]);
        bfrag[6] = f2bf(n1[2]); bfrag[7] = f2bf(n1[3]);

        float bb[16];
        bb[0]=q0[0];  bb[1]=q0[1];  bb[2]=q0[2];  bb[3]=q0[3];
        bb[4]=q1[0];  bb[5]=q1[1];  bb[6]=q1[2];  bb[7]=q1[3];
        bb[8]=q2[0];  bb[9]=q2[1];  bb[10]=q2[2]; bb[11]=q2[3];
        bb[12]=q3[0]; bb[13]=q3[1]; bb[14]=q3[2]; bb[15]=q3[3];

        f32x4 macc = {0.f,0.f,0.f,0.f};
        const f32x4 z = {0.f,0.f,0.f,0.f};
#pragma unroll
        for (int b = 0; b < 16; ++b) {
            f32x4 d = __builtin_amdgcn_mfma_f32_16x16x32_bf16(afr[b], bfrag, z, 0, 0, 0);
            macc[0] = fmaf(bb[b], d[0], macc[0]);
            macc[1] = fmaf(bb[b], d[1], macc[1]);
            macc[2] = fmaf(bb[b], d[2], macc[2]);
            macc[3] = fmaf(bb[b], d[3], macc[3]);
        }
        {   // bias channel (coefficient 1)
            f32x4 d = __builtin_amdgcn_mfma_f32_16x16x32_bf16(af16, bfrag, z, 0, 0, 0);
            macc[0] += d[0]; macc[1] += d[1]; macc[2] += d[2]; macc[3] += d[3];
        }

        // stage bond[t+1] into the other buffer (bv1 issued one iteration ago)
        *(f32x4*)bwB = bv1;

        // store current msg at CSR slot
        s16x4 mv;
        mv[0] = f2bf(macc[0]); mv[1] = f2bf(macc[1]);
        mv[2] = f2bf(macc[2]); mv[3] = f2bf(macc[3]);
        *(s16x4*)&msg[(long long)e0.y*32 + ibase] = mv;

        // rotate pipeline state
        e0 = e1; e1 = e2; bv1 = bv2; n0 = n0n; n1 = n1n;
        float* tw = bwA; bwA = bwB; bwB = tw;
        const float* tr = brA; brA = brB; brB = tr;
    }
}

// ---------------- phase B: per-atom gather-sum (atomic-free, 2x unroll) ----------------
__global__ __launch_bounds__(256) void gather_kernel(const short* __restrict__ msg,
                                                     const int* __restrict__ offsets,
                                                     float* __restrict__ out) {
    const int tid = threadIdx.x;
    const int a = blockIdx.x * 32 + (tid >> 3);
    const int sub = (tid & 7) * 4;
    if (a >= N_ATOMS) return;
    const int b0 = offsets[a], b1 = offsets[a + 1];
    f32x4 acc0 = {0.f, 0.f, 0.f, 0.f};
    f32x4 acc1 = {0.f, 0.f, 0.f, 0.f};
    int k = b0;
    for (; k + 1 < b1; k += 2) {
        s16x4 mv0 = *(const s16x4*)&msg[k*32 + sub];
        s16x4 mv1 = *(const s16x4*)&msg[(k+1)*32 + sub];
        acc0[0] += bf2f(mv0[0]); acc0[1] += bf2f(mv0[1]);
        acc0[2] += bf2f(mv0[2]); acc0[3] += bf2f(mv0[3]);
        acc1[0] += bf2f(mv1[0]); acc1[1] += bf2f(mv1[1]);
        acc1[2] += bf2f(mv1[2]); acc1[3] += bf2f(mv1[3]);
    }
    if (k < b1) {
        s16x4 mv0 = *(const s16x4*)&msg[k*32 + sub];
        acc0[0] += bf2f(mv0[0]); acc0[1] += bf2f(mv0[1]);
        acc0[2] += bf2f(mv0[2]); acc0[3] += bf2f(mv0[3]);
    }
    acc0[0] += acc1[0]; acc0[1] += acc1[1]; acc0[2] += acc1[2]; acc0[3] += acc1[3];
    *(f32x4*)&out[a*32 + sub] = acc0;
}

// ---------------- fallback (R1 atomic version, known-passing) ----------------
__global__ __launch_bounds__(256) void zero_out(f32x4* __restrict__ out) {
    int i = blockIdx.x * 256 + threadIdx.x;
    f32x4 z = {0.f, 0.f, 0.f, 0.f};
    out[i] = z;
}

__global__ __launch_bounds__(256, 4)
void edge_kernel_atomic(const float* __restrict__ atom, const float* __restrict__ bond,
                        const int2* __restrict__ pair, const float* __restrict__ kern,
                        const float* __restrict__ bias, float* __restrict__ out)
{
    __shared__ __align__(16) short alds[17*2*512];
    const int tid = threadIdx.x;
    for (int x = tid; x < 17*2*512; x += 256) {
        const int t = x & 7;
        const int l = (x >> 3) & 63;
        const int m = (x >> 9) & 1;
        const int b = x >> 10;
        const int i = m*16 + (l & 15);
        const int j = ((l >> 4) << 3) + t;
        const float v = (b < 16) ? kern[b*1024 + i*32 + j] : bias[i*32 + j];
        alds[x] = f2bf(v);
    }
    __syncthreads();
    const int wave = tid >> 6, lane = tid & 63;
    const int er = lane & 15, jg = lane >> 4;
    const int wid = blockIdx.x * 4 + wave;
    const int m = wid & 1, pid = wid >> 1;
    short8 afr[17];
#pragma unroll
    for (int b = 0; b < 17; ++b)
        afr[b] = *(const short8*)&alds[(b*2 + m)*512 + lane*8];
    const int ibase = m*16 + jg*4;
    for (int tile = pid; tile < N_TILES; tile += WAVE_PAIRS) {
        const int e = tile*16 + er;
        const int2 p = pair[e];
        const f32x4* arow = (const f32x4*)(atom + p.y * 32);
        const f32x4 n0 = arow[jg*2];
        const f32x4 n1 = arow[jg*2 + 1];
        short8 bfrag;
        bfrag[0] = f2bf(n0[0]); bfrag[1] = f2bf(n0[1]);
        bfrag[2] = f2bf(n0[2]); bfrag[3] = f2bf(n0[3]);
        bfrag[4] = f2bf(n1[0]); bfrag[5] = f2bf(n1[1]);
        bfrag[6] = f2bf(n1[2]); bfrag[7] = f2bf(n1[3]);
        const f32x4* brow = (const f32x4*)(bond + e * 16);
        const f32x4 q0 = brow[0], q1 = brow[1], q2 = brow[2], q3 = brow[3];
        float bb[17];
        bb[0]=q0[0];  bb[1]=q0[1];  bb[2]=q0[2];  bb[3]=q0[3];
        bb[4]=q1[0];  bb[5]=q1[1];  bb[6]=q1[2];  bb[7]=q1[3];
        bb[8]=q2[0];  bb[9]=q2[1];  bb[10]=q2[2]; bb[11]=q2[3];
        bb[12]=q3[0]; bb[13]=q3[1]; bb[14]=q3[2]; bb[15]=q3[3];
        bb[16]=1.0f;
        f32x4 macc = {0.f,0.f,0.f,0.f};
#pragma unroll
        for (int b = 0; b < 17; ++b) {
            f32x4 z = {0.f,0.f,0.f,0.f};
            f32x4 d = __builtin_amdgcn_mfma_f32_16x16x32_bf16(afr[b], bfrag, z, 0, 0, 0);
            macc[0] = fmaf(bb[b], d[0], macc[0]);
            macc[1] = fmaf(bb[b], d[1], macc[1]);
            macc[2] = fmaf(bb[b], d[2], macc[2]);
            macc[3] = fmaf(bb[b], d[3], macc[3]);
        }
        float* obase = out + p.x * 32 + ibase;
        atomicAdd(obase + 0, macc[0]);
        atomicAdd(obase + 1, macc[1]);
        atomicAdd(obase + 2, macc[2]);
        atomicAdd(obase + 3, macc[3]);
    }
}

extern "C" void kernel_launch(void* const* d_in, const int* in_sizes, int n_in,
                              void* d_out, int out_size, void* d_ws, size_t ws_size,
                              hipStream_t stream)
{
    (void)in_sizes; (void)n_in; (void)out_size;
    const float* atom = (const float*)d_in[0];
    const float* bond = (const float*)d_in[1];
    const int2*  pair = (const int2*)d_in[2];
    const float* kern = (const float*)d_in[3];
    const float* bias = (const float*)d_in[4];
    float* out = (float*)d_out;

    if (ws_size < WS_NEED) {
        zero_out<<<dim3(N_ATOMS*32/4/256), dim3(256), 0, stream>>>((f32x4*)out);
        edge_kernel_atomic<<<dim3(1024), dim3(256), 0, stream>>>(atom, bond, pair, kern, bias, out);
        return;
    }

    char* ws = (char*)d_ws;
    short* msg    = (short*)(ws + WS_MSG);
    int* offsets  = (int*)(ws + WS_OFFS);
    int* counts   = (int*)(ws + WS_COUNTS);
    int2* edata   = (int2*)(ws + WS_EDATA);
    int* rank     = (int*)(ws + WS_RANK);
    int* partials = (int*)(ws + WS_PART);

    const int eb = (N_EDGES + 255) / 256;          // 3125
    zero_ints<<<dim3((N_ATOMS + 255)/256), dim3(256), 0, stream>>>(counts, N_ATOMS);
    rank_kernel<<<dim3(eb), dim3(256), 0, stream>>>(pair, counts, rank);
    scan_part<<<dim3(N_CHUNKS), dim3(256), 0, stream>>>(counts, partials);
    scan_mid<<<dim3(1), dim3(512), 0, stream>>>(partials);
    scan_final<<<dim3(N_CHUNKS), dim3(256), 0, stream>>>(counts, partials, offsets);
    edata_kernel<<<dim3(eb), dim3(256), 0, stream>>>(pair, offsets, rank, edata);
    edge_msg_kernel<<<dim3(1024), dim3(256), 0, stream>>>(atom, bond, kern, bias, edata, msg);
    gather_kernel<<<dim3((N_ATOMS + 31)/32), dim3(256), 0, stream>>>(msg, offsets, out);
}